// Round 3
// baseline (23228.200 us; speedup 1.0000x reference)
//
#include <hip/hip_runtime.h>
#include <stdint.h>

#define N_SITES 144
#define NHID    256
#define NSAMP   1024
#define MB      4          // samples per block
#define TPB     1024       // phase A: 768 col-threads; phase B: 1024 (unit,sample) threads
#define NCOL    768

__device__ __forceinline__ uint32_t rotl32(uint32_t v, uint32_t r) {
    return (v << r) | (v >> (32u - r));
}

// JAX threefry2x32: 20 rounds, key injections every 4
__device__ __forceinline__ void threefry(uint32_t k0, uint32_t k1,
                                         uint32_t x0, uint32_t x1,
                                         uint32_t& o0, uint32_t& o1) {
    uint32_t ks0 = k0, ks1 = k1, ks2 = k0 ^ k1 ^ 0x1BD11BDAu;
    x0 += ks0; x1 += ks1;
#define RG4(a,b,c,d) \
    x0 += x1; x1 = rotl32(x1,a); x1 ^= x0; \
    x0 += x1; x1 = rotl32(x1,b); x1 ^= x0; \
    x0 += x1; x1 = rotl32(x1,c); x1 ^= x0; \
    x0 += x1; x1 = rotl32(x1,d); x1 ^= x0;
    RG4(13,15,26,6)  x0 += ks1; x1 += ks2 + 1u;
    RG4(17,29,16,24) x0 += ks2; x1 += ks0 + 2u;
    RG4(13,15,26,6)  x0 += ks0; x1 += ks1 + 3u;
    RG4(17,29,16,24) x0 += ks1; x1 += ks2 + 4u;
    RG4(13,15,26,6)  x0 += ks2; x1 += ks0 + 5u;
#undef RG4
    o0 = x0; o1 = x1;
}

__device__ __forceinline__ float gumbel_from_bits(uint32_t bits) {
#pragma clang fp contract(off)
    const float TINY = 1.17549435e-38f;          // finfo(f32).tiny
    uint32_t fb = (bits >> 9) | 0x3f800000u;
    float u = __uint_as_float(fb) - 1.0f;        // [0,1)
    u = u * (1.0f - TINY) + TINY;                // matches JAX uniform()
    u = fmaxf(TINY, u);
    return -logf(-logf(u));
}

__device__ __forceinline__ float bcast_lane(float v, int l) {
    return __int_as_float(__builtin_amdgcn_readlane(__float_as_int(v), l));
}

__global__ __launch_bounds__(TPB, 1)
void rnn_sample_kernel(const float* __restrict__ kern,   // [2,768]
                       const float* __restrict__ rec,    // [256,768]
                       const float* __restrict__ bias,   // [2,768]
                       const float* __restrict__ dw,     // [256,2]
                       const float* __restrict__ db,     // [2]
                       float* __restrict__ out)          // samples[1024*144] ++ logP[1024]
{
    const int t    = threadIdx.x;
    const int blk  = blockIdx.x;
    const int b0   = blk * MB;
    const int lane = t & 63;
    const int u    = t & 255;              // hidden unit (phase B/C)
    const int m    = t >> 8;               // sample     (phase B/C)
    const int wj   = (t >> 6) & 3;         // 64-chunk of u within sample

    __shared__ float    hs4[NHID][4];       // h[k][sample] (float4 rows, 4 KB)
    __shared__ float    pacc[MB][NCOL];     // phase-A partials (12 KB)
    __shared__ uint32_t keyA[N_SITES], keyB[N_SITES];
    __shared__ float    wred[4][8];         // dense partials [u-chunk][2m+c]
    __shared__ int      sPrev[MB];
    __shared__ float    lgP[MB];

    // ---- per-thread constants for unit u (redundant across the 4 m's; cached) ----
    const float kz0 = kern[u],       kr0 = kern[u + 256], kn0 = kern[u + 512];
    const float kz1 = kern[768 + u], kr1 = kern[768 + u + 256], kn1 = kern[768 + u + 512];
    const float b0z = bias[u],       b0r = bias[u + 256], b0n = bias[u + 512];
    const float b1z = bias[768 + u], b1r = bias[768 + u + 256], b1n = bias[768 + u + 512];
    const float dwa = dw[2 * u], dwb = dw[2 * u + 1];
    const float dba = db[0],     dbb = db[1];

    if (t < NHID) { hs4[t][0] = 0.f; hs4[t][1] = 0.f; hs4[t][2] = 0.f; hs4[t][3] = 0.f; }
    if (t < MB) { sPrev[t] = -1; lgP[t] = 0.f; }
    if (t < N_SITES) {
        uint32_t o0, o1;
        threefry(0u, 42u, 0u, (uint32_t)t, o0, o1);   // foldlike split: counter = n
        keyA[t] = o0; keyB[t] = o1;
    }
    __syncthreads();

    const float4* hrow = (const float4*)&hs4[0][0];

    for (int n = 0; n < N_SITES; ++n) {
        // ---- phase A: cols on threads 0..767; h broadcast via v_readlane (VALU),
        //      not LDS broadcast (shared DS pipe). k-chain order bit-identical. ----
        if (t < NCOL) {
            float a0 = 0.f, a1 = 0.f, a2 = 0.f, a3 = 0.f;
            // coalesced: lane l holds h4 of units {l, 64+l, 128+l, 192+l}
            float4 hr0 = hrow[lane];
            float4 hr1 = hrow[64 + lane];
            float4 hr2 = hrow[128 + lane];
            float4 hr3 = hrow[192 + lane];
            const float* rp = rec + t;
#define KSTEP(HR, L) { \
            float w = rp[0]; rp += NCOL; \
            float h0 = bcast_lane(HR.x, L); \
            float h1 = bcast_lane(HR.y, L); \
            float h2 = bcast_lane(HR.z, L); \
            float h3 = bcast_lane(HR.w, L); \
            a0 = fmaf(h0, w, a0); \
            a1 = fmaf(h1, w, a1); \
            a2 = fmaf(h2, w, a2); \
            a3 = fmaf(h3, w, a3); }
#pragma unroll
            for (int l = 0; l < 64; ++l) KSTEP(hr0, l)
#pragma unroll
            for (int l = 0; l < 64; ++l) KSTEP(hr1, l)
#pragma unroll
            for (int l = 0; l < 64; ++l) KSTEP(hr2, l)
#pragma unroll
            for (int l = 0; l < 64; ++l) KSTEP(hr3, l)
#undef KSTEP
            pacc[0][t] = a0; pacc[1][t] = a1; pacc[2][t] = a2; pacc[3][t] = a3;
        }
        __syncthreads();   // B1: pacc ready; all hs4 reads complete

        // ---- phase B: one (unit u, sample m) per thread — same scalar exprs ----
        float hnew;
        {
#pragma clang fp contract(off)
            const int sp = sPrev[m];
            float xz = (sp == 0) ? kz0 : ((sp == 1) ? kz1 : 0.f);
            float xr = (sp == 0) ? kr0 : ((sp == 1) ? kr1 : 0.f);
            float xh = (sp == 0) ? kn0 : ((sp == 1) ? kn1 : 0.f);
            xz = xz + b0z;  xr = xr + b0r;  xh = xh + b0n;
            const float hz = pacc[m][u]       + b1z;
            const float hr = pacc[m][u + 256] + b1r;
            const float hn = pacc[m][u + 512] + b1n;
            const float z = 1.0f / (1.0f + expf(-(xz + hz)));
            const float r = 1.0f / (1.0f + expf(-(xr + hr)));
            const float rhn = r * hn;
            const float hh = tanhf(xh + rhn);
            const float hold = hs4[u][m];
            hnew = z * hold + (1.0f - z) * hh;
        }
        hs4[u][m] = hnew;

        // ---- phase C: dense partials; wave (m, wj) reduces u-chunk wj, lane↔u
        //      mapping and shfl tree identical to the verified kernel ----
        {
            float va = hnew * dwa;
            float vb = hnew * dwb;
#pragma unroll
            for (int off = 32; off > 0; off >>= 1) {
                va += __shfl_xor(va, off, 64);
                vb += __shfl_xor(vb, off, 64);
            }
            if (lane == 0) { wred[wj][2 * m] = va; wred[wj][2 * m + 1] = vb; }
        }
        __syncthreads();   // B2: wred ready

        // ---- phase D: logits + gumbel + categorical + logP (4 threads) ----
        if (t < MB) {
            const int mm = t;
            float l0 = wred[0][2 * mm] + wred[1][2 * mm] + wred[2][2 * mm] + wred[3][2 * mm];
            float l1 = wred[0][2 * mm + 1] + wred[1][2 * mm + 1] + wred[2][2 * mm + 1] + wred[3][2 * mm + 1];
            uint32_t o0a, o1a, o0b, o1b;
            const uint32_t fbase = 2u * (uint32_t)(b0 + mm);
            threefry(keyA[n], keyB[n], 0u, fbase,      o0a, o1a);
            threefry(keyA[n], keyB[n], 0u, fbase + 1u, o0b, o1b);
            const float g0 = gumbel_from_bits(o0a ^ o1a);
            const float g1 = gumbel_from_bits(o0b ^ o1b);
            {
#pragma clang fp contract(off)
                l0 = l0 + dba;
                l1 = l1 + dbb;
                const float mx = fmaxf(l0, l1);
                const float e0 = expf(l0 - mx), e1 = expf(l1 - mx);
                const float den = e0 + e1;
                const float lp0 = logf(1e-10f + e0 / den);
                const float lp1 = logf(1e-10f + e1 / den);
                const float v0 = g0 + lp0;
                const float v1 = g1 + lp1;
                const int s = (v1 > v0) ? 1 : 0;   // argmax, first-index tie-break
                sPrev[mm] = s;
                lgP[mm] = lgP[mm] + (s ? lp1 : lp0);
                out[(size_t)(b0 + mm) * N_SITES + n] = (float)s;
            }
        }
        __syncthreads();   // B3: sPrev/hs4 stable for next step
    }

    if (t < MB) out[(size_t)NSAMP * N_SITES + (b0 + t)] = lgP[t];
}

extern "C" void kernel_launch(void* const* d_in, const int* in_sizes, int n_in,
                              void* d_out, int out_size, void* d_ws, size_t ws_size,
                              hipStream_t stream) {
    (void)in_sizes; (void)n_in; (void)d_ws; (void)ws_size; (void)out_size;
    const float* kern = (const float*)d_in[0];
    const float* rec  = (const float*)d_in[1];
    const float* bias = (const float*)d_in[2];
    const float* dwp  = (const float*)d_in[3];
    const float* dbp  = (const float*)d_in[4];
    float* out = (float*)d_out;
    rnn_sample_kernel<<<NSAMP / MB, TPB, 0, stream>>>(kern, rec, bias, dwp, dbp, out);
}

// Round 4
// 2991.389 us; speedup vs baseline: 7.7650x; 7.7650x over previous
//
#include <hip/hip_runtime.h>
#include <stdint.h>

#define N_SITES 144
#define NHID    256
#define NSAMP   1024
#define MB      4          // samples per block
#define TPB     768        // one gate-column per thread; 12 waves = 3 waves/SIMD
#define NCOL    768

__device__ __forceinline__ uint32_t rotl32(uint32_t v, uint32_t r) {
    return (v << r) | (v >> (32u - r));
}

// JAX threefry2x32: 20 rounds, key injections every 4
__device__ __forceinline__ void threefry(uint32_t k0, uint32_t k1,
                                         uint32_t x0, uint32_t x1,
                                         uint32_t& o0, uint32_t& o1) {
    uint32_t ks0 = k0, ks1 = k1, ks2 = k0 ^ k1 ^ 0x1BD11BDAu;
    x0 += ks0; x1 += ks1;
#define RG4(a,b,c,d) \
    x0 += x1; x1 = rotl32(x1,a); x1 ^= x0; \
    x0 += x1; x1 = rotl32(x1,b); x1 ^= x0; \
    x0 += x1; x1 = rotl32(x1,c); x1 ^= x0; \
    x0 += x1; x1 = rotl32(x1,d); x1 ^= x0;
    RG4(13,15,26,6)  x0 += ks1; x1 += ks2 + 1u;
    RG4(17,29,16,24) x0 += ks2; x1 += ks0 + 2u;
    RG4(13,15,26,6)  x0 += ks0; x1 += ks1 + 3u;
    RG4(17,29,16,24) x0 += ks1; x1 += ks2 + 4u;
    RG4(13,15,26,6)  x0 += ks2; x1 += ks0 + 5u;
#undef RG4
    o0 = x0; o1 = x1;
}

__device__ __forceinline__ float gumbel_from_bits(uint32_t bits) {
#pragma clang fp contract(off)
    const float TINY = 1.17549435e-38f;          // finfo(f32).tiny
    uint32_t fb = (bits >> 9) | 0x3f800000u;
    float u = __uint_as_float(fb) - 1.0f;        // [0,1)
    u = u * (1.0f - TINY) + TINY;                // matches JAX uniform()
    u = fmaxf(TINY, u);
    return -logf(-logf(u));
}

__device__ __forceinline__ float bcast_lane(float v, int l) {
    // v_readlane_b32 with SGPR lane index (l is wave-uniform loop var)
    return __int_as_float(__builtin_amdgcn_readlane(__float_as_int(v), l));
}

__global__ __launch_bounds__(TPB, 1)
void rnn_sample_kernel(const float* __restrict__ kern,   // [2,768]
                       const float* __restrict__ rec,    // [256,768]
                       const float* __restrict__ bias,   // [2,768]
                       const float* __restrict__ dw,     // [256,2]
                       const float* __restrict__ db,     // [2]
                       float* __restrict__ out)          // samples[1024*144] ++ logP[1024]
{
    const int t    = threadIdx.x;          // 0..767 == gate column index
    const int blk  = blockIdx.x;
    const int b0   = blk * MB;
    const int wv   = t >> 6;               // wave id (phase C uses 0..3)
    const int lane = t & 63;

    __shared__ float4   hs4[NHID];          // h[k] packed over 4 samples (4 KB)
    __shared__ float    pacc[MB][TPB];      // phase-A partials, [sample][col] (12 KB)
    __shared__ uint32_t keyA[N_SITES], keyB[N_SITES];
    __shared__ float    wred[4][8];         // per-wave dense partials (waves 0..3)
    __shared__ int      sPrev[MB];
    __shared__ float    lgP[MB];

    // ---- per-thread constants (threads 0..255 only: gate triples) ----
    float kz0 = 0.f, kr0 = 0.f, kn0 = 0.f, kz1 = 0.f, kr1 = 0.f, kn1 = 0.f;
    float b0z = 0.f, b0r = 0.f, b0n = 0.f, b1z = 0.f, b1r = 0.f, b1n = 0.f;
    float dwa = 0.f, dwb = 0.f, dba = 0.f, dbb = 0.f;
    if (t < NHID) {
        const int c0 = t, c1 = t + 256, c2 = t + 512;
        kz0 = kern[c0];       kr0 = kern[c1];       kn0 = kern[c2];
        kz1 = kern[768 + c0]; kr1 = kern[768 + c1]; kn1 = kern[768 + c2];
        b0z = bias[c0];       b0r = bias[c1];       b0n = bias[c2];
        b1z = bias[768 + c0]; b1r = bias[768 + c1]; b1n = bias[768 + c2];
        dwa = dw[2 * t];      dwb = dw[2 * t + 1];
        dba = db[0];          dbb = db[1];
        hs4[t] = make_float4(0.f, 0.f, 0.f, 0.f);
    }
    if (t < MB) { sPrev[t] = -1; lgP[t] = 0.f; }
    if (t < N_SITES) {
        uint32_t o0, o1;
        threefry(0u, 42u, 0u, (uint32_t)t, o0, o1);   // foldlike split: counter = n
        keyA[t] = o0; keyB[t] = o1;
    }
    __syncthreads();

    const float4* hrow = (const float4*)hs4;

    for (int n = 0; n < N_SITES; ++n) {
        // ---- phase A: one column per thread; h fetched coalesced (4 ds_read_b128
        //      per thread per step), broadcast via v_readlane (VALU pipe, not DS).
        //      k-chain order (64c+l ascending) and fmaf chain bit-identical to R2. ----
        float a0 = 0.f, a1 = 0.f, a2 = 0.f, a3 = 0.f;
        {
            // lane l holds h4 of units {l, 64+l, 128+l, 192+l}
            float4 hr0 = hrow[lane];
            float4 hr1 = hrow[64 + lane];
            float4 hr2 = hrow[128 + lane];
            float4 hr3 = hrow[192 + lane];
            const float* rp = rec + t;
#define CHUNK(HR) \
            _Pragma("unroll 8") \
            for (int l = 0; l < 64; ++l) { \
                float w = rp[0]; rp += NCOL; \
                float h0 = bcast_lane(HR.x, l); \
                float h1 = bcast_lane(HR.y, l); \
                float h2 = bcast_lane(HR.z, l); \
                float h3 = bcast_lane(HR.w, l); \
                a0 = fmaf(h0, w, a0); \
                a1 = fmaf(h1, w, a1); \
                a2 = fmaf(h2, w, a2); \
                a3 = fmaf(h3, w, a3); \
            }
            CHUNK(hr0)
            CHUNK(hr1)
            CHUNK(hr2)
            CHUNK(hr3)
#undef CHUNK
        }
        pacc[0][t] = a0; pacc[1][t] = a1; pacc[2][t] = a2; pacc[3][t] = a3;
        __syncthreads();   // B1: pacc ready; all hs4 reads complete

        // ---- phases B+C: threads 0..255 (gates, h update, dense partials) ----
        float hnew[MB];
        if (t < NHID) {
            float4 ho = hs4[t];
            float hold[MB] = { ho.x, ho.y, ho.z, ho.w };
            {
#pragma clang fp contract(off)
#pragma unroll
                for (int m = 0; m < MB; ++m) {
                    const int sp = sPrev[m];
                    float xz = (sp == 0) ? kz0 : ((sp == 1) ? kz1 : 0.f);
                    float xr = (sp == 0) ? kr0 : ((sp == 1) ? kr1 : 0.f);
                    float xh = (sp == 0) ? kn0 : ((sp == 1) ? kn1 : 0.f);
                    xz = xz + b0z;  xr = xr + b0r;  xh = xh + b0n;
                    const float hz = pacc[m][t]       + b1z;
                    const float hr = pacc[m][t + 256] + b1r;
                    const float hn = pacc[m][t + 512] + b1n;
                    const float z = 1.0f / (1.0f + expf(-(xz + hz)));
                    const float r = 1.0f / (1.0f + expf(-(xr + hr)));
                    const float rhn = r * hn;
                    const float hh = tanhf(xh + rhn);
                    hnew[m] = z * hold[m] + (1.0f - z) * hh;
                }
            }
            hs4[t] = make_float4(hnew[0], hnew[1], hnew[2], hnew[3]);

            // dense logits partial reduction (h @ dense_w), waves 0..3
#pragma unroll
            for (int m = 0; m < MB; ++m) {
                float va = hnew[m] * dwa;
                float vb = hnew[m] * dwb;
#pragma unroll
                for (int off = 32; off > 0; off >>= 1) {
                    va += __shfl_xor(va, off, 64);
                    vb += __shfl_xor(vb, off, 64);
                }
                if (lane == 0) { wred[wv][2 * m] = va; wred[wv][2 * m + 1] = vb; }
            }
        }
        __syncthreads();   // B2: wred ready

        // ---- phase D: logits + gumbel + categorical + logP (4 threads) ----
        if (t < MB) {
            const int m = t;
            float l0 = wred[0][2 * m] + wred[1][2 * m] + wred[2][2 * m] + wred[3][2 * m];
            float l1 = wred[0][2 * m + 1] + wred[1][2 * m + 1] + wred[2][2 * m + 1] + wred[3][2 * m + 1];
            uint32_t o0a, o1a, o0b, o1b;
            const uint32_t fbase = 2u * (uint32_t)(b0 + m);
            threefry(keyA[n], keyB[n], 0u, fbase,      o0a, o1a);
            threefry(keyA[n], keyB[n], 0u, fbase + 1u, o0b, o1b);
            const float g0 = gumbel_from_bits(o0a ^ o1a);
            const float g1 = gumbel_from_bits(o0b ^ o1b);
            {
#pragma clang fp contract(off)
                l0 = l0 + dba;
                l1 = l1 + dbb;
                const float mx = fmaxf(l0, l1);
                const float e0 = expf(l0 - mx), e1 = expf(l1 - mx);
                const float den = e0 + e1;
                const float lp0 = logf(1e-10f + e0 / den);
                const float lp1 = logf(1e-10f + e1 / den);
                const float v0 = g0 + lp0;
                const float v1 = g1 + lp1;
                const int s = (v1 > v0) ? 1 : 0;   // argmax, first-index tie-break
                sPrev[m] = s;
                lgP[m] = lgP[m] + (s ? lp1 : lp0);
                out[(size_t)(b0 + m) * N_SITES + n] = (float)s;
            }
        }
        __syncthreads();   // B3: sPrev/hs4 stable for next step
    }

    if (t < MB) out[(size_t)NSAMP * N_SITES + (b0 + t)] = lgP[t];
}

extern "C" void kernel_launch(void* const* d_in, const int* in_sizes, int n_in,
                              void* d_out, int out_size, void* d_ws, size_t ws_size,
                              hipStream_t stream) {
    (void)in_sizes; (void)n_in; (void)d_ws; (void)ws_size; (void)out_size;
    const float* kern = (const float*)d_in[0];
    const float* rec  = (const float*)d_in[1];
    const float* bias = (const float*)d_in[2];
    const float* dwp  = (const float*)d_in[3];
    const float* dbp  = (const float*)d_in[4];
    float* out = (float*)d_out;
    rnn_sample_kernel<<<NSAMP / MB, TPB, 0, stream>>>(kern, rec, bias, dwp, dbp, out);
}

// Round 5
// 1708.196 us; speedup vs baseline: 13.5981x; 1.7512x over previous
//
#include <hip/hip_runtime.h>
#include <stdint.h>

#define N_SITES 144
#define NHID    256
#define NSAMP   1024
#define MB      4          // samples per block
#define TPB     384        // 6 waves; phase A: 2 cols/thread (DS traffic halved vs C=1)
#define NCOL    768

__device__ __forceinline__ uint32_t rotl32(uint32_t v, uint32_t r) {
    return (v << r) | (v >> (32u - r));
}

// JAX threefry2x32: 20 rounds, key injections every 4
__device__ __forceinline__ void threefry(uint32_t k0, uint32_t k1,
                                         uint32_t x0, uint32_t x1,
                                         uint32_t& o0, uint32_t& o1) {
    uint32_t ks0 = k0, ks1 = k1, ks2 = k0 ^ k1 ^ 0x1BD11BDAu;
    x0 += ks0; x1 += ks1;
#define RG4(a,b,c,d) \
    x0 += x1; x1 = rotl32(x1,a); x1 ^= x0; \
    x0 += x1; x1 = rotl32(x1,b); x1 ^= x0; \
    x0 += x1; x1 = rotl32(x1,c); x1 ^= x0; \
    x0 += x1; x1 = rotl32(x1,d); x1 ^= x0;
    RG4(13,15,26,6)  x0 += ks1; x1 += ks2 + 1u;
    RG4(17,29,16,24) x0 += ks2; x1 += ks0 + 2u;
    RG4(13,15,26,6)  x0 += ks0; x1 += ks1 + 3u;
    RG4(17,29,16,24) x0 += ks1; x1 += ks2 + 4u;
    RG4(13,15,26,6)  x0 += ks2; x1 += ks0 + 5u;
#undef RG4
    o0 = x0; o1 = x1;
}

__device__ __forceinline__ float gumbel_from_bits(uint32_t bits) {
#pragma clang fp contract(off)
    const float TINY = 1.17549435e-38f;          // finfo(f32).tiny
    uint32_t fb = (bits >> 9) | 0x3f800000u;
    float u = __uint_as_float(fb) - 1.0f;        // [0,1)
    u = u * (1.0f - TINY) + TINY;                // matches JAX uniform()
    u = fmaxf(TINY, u);
    return -logf(-logf(u));
}

__global__ __launch_bounds__(TPB, 1)
void rnn_sample_kernel(const float* __restrict__ kern,   // [2,768]
                       const float* __restrict__ rec,    // [256,768]
                       const float* __restrict__ bias,   // [2,768]
                       const float* __restrict__ dw,     // [256,2]
                       const float* __restrict__ db,     // [2]
                       float* __restrict__ out)          // samples[1024*144] ++ logP[1024]
{
    const int t    = threadIdx.x;          // phase A: cols {t, t+384}
    const int blk  = blockIdx.x;
    const int b0   = blk * MB;
    const int wv   = t >> 6;               // wave id (phase C uses 0..3)
    const int lane = t & 63;

    __shared__ float4   hs4[NHID];          // h[k] packed over 4 samples (4 KB)
    __shared__ float    pacc[MB][NCOL];     // phase-A partials, [sample][col] (12 KB)
    __shared__ uint32_t keyA[N_SITES], keyB[N_SITES];
    __shared__ float    wred[4][8];         // per-wave dense partials (waves 0..3)
    __shared__ int      sPrev[MB];
    __shared__ float    lgP[MB];

    // ---- per-thread constants (threads 0..255 only: gate triples) ----
    float kz0 = 0.f, kr0 = 0.f, kn0 = 0.f, kz1 = 0.f, kr1 = 0.f, kn1 = 0.f;
    float b0z = 0.f, b0r = 0.f, b0n = 0.f, b1z = 0.f, b1r = 0.f, b1n = 0.f;
    float dwa = 0.f, dwb = 0.f, dba = 0.f, dbb = 0.f;
    if (t < NHID) {
        const int c0 = t, c1 = t + 256, c2 = t + 512;
        kz0 = kern[c0];       kr0 = kern[c1];       kn0 = kern[c2];
        kz1 = kern[768 + c0]; kr1 = kern[768 + c1]; kn1 = kern[768 + c2];
        b0z = bias[c0];       b0r = bias[c1];       b0n = bias[c2];
        b1z = bias[768 + c0]; b1r = bias[768 + c1]; b1n = bias[768 + c2];
        dwa = dw[2 * t];      dwb = dw[2 * t + 1];
        dba = db[0];          dbb = db[1];
        hs4[t] = make_float4(0.f, 0.f, 0.f, 0.f);
    }
    if (t < MB) { sPrev[t] = -1; lgP[t] = 0.f; }
    if (t < N_SITES) {
        uint32_t o0, o1;
        threefry(0u, 42u, 0u, (uint32_t)t, o0, o1);   // foldlike split: counter = n
        keyA[t] = o0; keyB[t] = o1;
    }
    __syncthreads();

    for (int n = 0; n < N_SITES; ++n) {
        // ---- phase A: two columns per thread {t, t+384}; h4 broadcast read once
        //      per k, reused for both columns. Per-column k-chain order and fmaf
        //      sequence bit-identical to the verified R2 kernel. ----
        float a00 = 0.f, a10 = 0.f, a20 = 0.f, a30 = 0.f;   // col t
        float a01 = 0.f, a11 = 0.f, a21 = 0.f, a31 = 0.f;   // col t+384
        {
            const float* rp = rec + t;
#pragma unroll 8
            for (int k = 0; k < NHID; ++k) {
                float4 h4 = hs4[k];          // one ds_read_b128 broadcast per k
                float w0 = rp[0];
                float w1 = rp[384];
                rp += NCOL;
                a00 = fmaf(h4.x, w0, a00);
                a10 = fmaf(h4.y, w0, a10);
                a20 = fmaf(h4.z, w0, a20);
                a30 = fmaf(h4.w, w0, a30);
                a01 = fmaf(h4.x, w1, a01);
                a11 = fmaf(h4.y, w1, a11);
                a21 = fmaf(h4.z, w1, a21);
                a31 = fmaf(h4.w, w1, a31);
            }
        }
        pacc[0][t] = a00; pacc[1][t] = a10; pacc[2][t] = a20; pacc[3][t] = a30;
        pacc[0][t + 384] = a01; pacc[1][t + 384] = a11;
        pacc[2][t + 384] = a21; pacc[3][t + 384] = a31;
        __syncthreads();   // B1: pacc + sPrev (from prev step's D) published

        // ---- phases B+C: threads 0..255 (gates, h update, dense partials) ----
        float hnew[MB];
        if (t < NHID) {
            float4 ho = hs4[t];
            float hold[MB] = { ho.x, ho.y, ho.z, ho.w };
            {
#pragma clang fp contract(off)
#pragma unroll
                for (int m = 0; m < MB; ++m) {
                    const int sp = sPrev[m];
                    float xz = (sp == 0) ? kz0 : ((sp == 1) ? kz1 : 0.f);
                    float xr = (sp == 0) ? kr0 : ((sp == 1) ? kr1 : 0.f);
                    float xh = (sp == 0) ? kn0 : ((sp == 1) ? kn1 : 0.f);
                    xz = xz + b0z;  xr = xr + b0r;  xh = xh + b0n;
                    const float hz = pacc[m][t]       + b1z;
                    const float hr = pacc[m][t + 256] + b1r;
                    const float hn = pacc[m][t + 512] + b1n;
                    const float z = 1.0f / (1.0f + expf(-(xz + hz)));
                    const float r = 1.0f / (1.0f + expf(-(xr + hr)));
                    const float rhn = r * hn;
                    const float hh = tanhf(xh + rhn);
                    hnew[m] = z * hold[m] + (1.0f - z) * hh;
                }
            }
            hs4[t] = make_float4(hnew[0], hnew[1], hnew[2], hnew[3]);

            // dense logits partial reduction (h @ dense_w), waves 0..3
#pragma unroll
            for (int m = 0; m < MB; ++m) {
                float va = hnew[m] * dwa;
                float vb = hnew[m] * dwb;
#pragma unroll
                for (int off = 32; off > 0; off >>= 1) {
                    va += __shfl_xor(va, off, 64);
                    vb += __shfl_xor(vb, off, 64);
                }
                if (lane == 0) { wred[wv][2 * m] = va; wred[wv][2 * m + 1] = vb; }
            }
        }
        __syncthreads();   // B2: wred + hs4(new) published

        // ---- phase D: 4 threads; overlaps with next step's phase A on other
        //      waves (no trailing barrier — sPrev is consumed only after B1). ----
        if (t < MB) {
            const int m = t;
            float l0 = wred[0][2 * m] + wred[1][2 * m] + wred[2][2 * m] + wred[3][2 * m];
            float l1 = wred[0][2 * m + 1] + wred[1][2 * m + 1] + wred[2][2 * m + 1] + wred[3][2 * m + 1];
            uint32_t o0a, o1a, o0b, o1b;
            const uint32_t fbase = 2u * (uint32_t)(b0 + m);
            threefry(keyA[n], keyB[n], 0u, fbase,      o0a, o1a);
            threefry(keyA[n], keyB[n], 0u, fbase + 1u, o0b, o1b);
            const float g0 = gumbel_from_bits(o0a ^ o1a);
            const float g1 = gumbel_from_bits(o0b ^ o1b);
            {
#pragma clang fp contract(off)
                l0 = l0 + dba;
                l1 = l1 + dbb;
                const float mx = fmaxf(l0, l1);
                const float e0 = expf(l0 - mx), e1 = expf(l1 - mx);
                const float den = e0 + e1;
                const float lp0 = logf(1e-10f + e0 / den);
                const float lp1 = logf(1e-10f + e1 / den);
                const float v0 = g0 + lp0;
                const float v1 = g1 + lp1;
                const int s = (v1 > v0) ? 1 : 0;   // argmax, first-index tie-break
                sPrev[m] = s;
                lgP[m] = lgP[m] + (s ? lp1 : lp0);
                out[(size_t)(b0 + m) * N_SITES + n] = (float)s;
            }
        }
        // NOTE: no barrier here. Next phase A reads hs4 (stable since B2) and
        // writes pacc (WAR-safe: phase B's pacc reads completed before B2).
        // sPrev(n) is read only after the next B1.
    }

    __syncthreads();
    if (t < MB) out[(size_t)NSAMP * N_SITES + (b0 + t)] = lgP[t];
}

extern "C" void kernel_launch(void* const* d_in, const int* in_sizes, int n_in,
                              void* d_out, int out_size, void* d_ws, size_t ws_size,
                              hipStream_t stream) {
    (void)in_sizes; (void)n_in; (void)d_ws; (void)ws_size; (void)out_size;
    const float* kern = (const float*)d_in[0];
    const float* rec  = (const float*)d_in[1];
    const float* bias = (const float*)d_in[2];
    const float* dwp  = (const float*)d_in[3];
    const float* dbp  = (const float*)d_in[4];
    float* out = (float*)d_out;
    rnn_sample_kernel<<<NSAMP / MB, TPB, 0, stream>>>(kern, rec, bias, dwp, dbp, out);
}